// Round 17
// baseline (61.788 us; speedup 1.0000x reference)
//
#include <hip/hip_runtime.h>
#include <stdint.h>
#include <stddef.h>

#define E_DIM 1024

typedef __bf16 v8bf __attribute__((ext_vector_type(8)));
typedef float v4f __attribute__((ext_vector_type(4)));

__device__ __forceinline__ unsigned short f2bf(float x) {
  unsigned int u = __builtin_bit_cast(unsigned int, x);
  u += 0x7fffu + ((u >> 16) & 1u);
  return (unsigned short)(u >> 16);
}

// XOR swizzle for LDS rows >= 128B (involution; both-sides-or-neither).
template <int RB>
__device__ __forceinline__ int swz(int r, int c) {
  if constexpr (RB >= 128) return c ^ ((r & 7) << 4);
  else return c;
}

// constexpr-dispatched s_waitcnt vmcnt(N)
template <int N>
__device__ __forceinline__ void waitcnt_vm() {
  static_assert(N == 0 || N == 4 || N == 8 || N == 12, "add literal");
  if constexpr (N == 0)  asm volatile("s_waitcnt vmcnt(0)" ::: "memory");
  if constexpr (N == 4)  asm volatile("s_waitcnt vmcnt(4)" ::: "memory");
  if constexpr (N == 8)  asm volatile("s_waitcnt vmcnt(8)" ::: "memory");
  if constexpr (N == 12) asm volatile("s_waitcnt vmcnt(12)" ::: "memory");
}

// bf16 global tile (ROWS x BK) -> LDS via global_load_lds, source pre-swizzled.
template <int ROWS, int BK>
__device__ __forceinline__ void stageg(const unsigned short* __restrict__ G, int g0,
                                       int ldg, int k0, char* L, int wid, int lane) {
  constexpr int RB = BK * 2;
  constexpr int ITERS = (ROWS * RB) / 4096;
#pragma unroll
  for (int it = 0; it < ITERS; ++it) {
    int lbase = it * 4096 + wid * 1024;   // wave-uniform LDS byte base
    int lin = lbase + lane * 16;
    int r = lin / RB, cb = lin % RB;
    int gcb = swz<RB>(r, cb);
    const char* g = (const char*)G + ((size_t)(g0 + r) * ldg + k0) * 2 + gcb;
    __builtin_amdgcn_global_load_lds((const __attribute__((address_space(1))) void*)g,
                                     (__attribute__((address_space(3))) void*)(L + lbase),
                                     16, 0, 0);
  }
}

template <int RB>
__device__ __forceinline__ v8bf frag_bf16(const char* L, int r, int kelem) {
  int o = swz<RB>(r, kelem * 2);
  return *(const v8bf*)(L + r * RB + o);
}

// one K-tile of MFMA work from bf16 LDS buffers
template <int BM, int BN, int BK, int FM, int FN>
__device__ __forceinline__ void compute_tile(const char* Al, const char* Bl,
                                             v4f (&acc)[FM][FN],
                                             int wr, int wc, int lr, int kg) {
  constexpr int RBA = BK * 2, RBB = BK * 2;
  constexpr int TMW = BM / 2, TNW = BN / 2;
#pragma unroll
  for (int kk = 0; kk < BK / 32; ++kk) {
    const int ke = kk * 32 + kg * 8;
    v8bf a[FM], b[FN];
#pragma unroll
    for (int mi = 0; mi < FM; ++mi)
      a[mi] = frag_bf16<RBA>(Al, wr * TMW + mi * 16 + lr, ke);
#pragma unroll
    for (int ni = 0; ni < FN; ++ni)
      b[ni] = frag_bf16<RBB>(Bl, wc * TNW + ni * 16 + lr, ke);
#pragma unroll
    for (int mi = 0; mi < FM; ++mi)
#pragma unroll
      for (int ni = 0; ni < FN; ++ni)
        acc[mi][ni] = __builtin_amdgcn_mfma_f32_16x16x32_bf16(a[mi], b[ni], acc[mi][ni], 0, 0, 0);
  }
}

// load a 64x64 fp32 tile into 4 float4 regs (coalesced; 16 float4 per row)
__device__ __forceinline__ void ldf32(const float* __restrict__ G, int g0, int ldg,
                                      int c0, int tid, float4 (&r)[4]) {
#pragma unroll
  for (int p = 0; p < 4; ++p) {
    int i4 = p * 256 + tid;
    int row = i4 >> 4, c4 = i4 & 15;
    r[p] = *(const float4*)(G + (size_t)(g0 + row) * ldg + c0 + c4 * 4);
  }
}

// cvt + straight write into 64-row RB=128 swizzled bf16 LDS tile
__device__ __forceinline__ void wrf32(const float4 (&r)[4], char* L, int tid) {
#pragma unroll
  for (int p = 0; p < 4; ++p) {
    int i4 = p * 256 + tid;
    int row = i4 >> 4, c4 = i4 & 15;
    ushort4 u;
    u.x = f2bf(r[p].x); u.y = f2bf(r[p].y); u.z = f2bf(r[p].z); u.w = f2bf(r[p].w);
    *(ushort4*)(L + row * 128 + swz<128>(row, c4 * 8)) = u;
  }
}

// cvt + TRANSPOSED write: reg element (row kk, col m=c4*4+j) -> LDS[m][kk]
__device__ __forceinline__ void wrf32T(const float4 (&r)[4], char* L, int tid) {
#pragma unroll
  for (int p = 0; p < 4; ++p) {
    int i4 = p * 256 + tid;
    int kk = i4 >> 4, c4 = i4 & 15;
    const float* f = (const float*)&r[p];
#pragma unroll
    for (int j = 0; j < 4; ++j) {
      int m = c4 * 4 + j;
      *(unsigned short*)(L + m * 128 + swz<128>(m, kk * 2)) = f2bf(f[j]);
    }
  }
}

// cvt 4096 fp32 -> bf16 per block; i0 = blkrel * 1024 + tid
__device__ __forceinline__ void cvt4(const float4* __restrict__ src,
                                     ushort4* __restrict__ dst, int i0) {
#pragma unroll
  for (int j = 0; j < 4; ++j) {
    int i = i0 + j * 256;
    float4 f = src[i];
    ushort4 u;
    u.x = f2bf(f.x); u.y = f2bf(f.y); u.z = f2bf(f.z); u.w = f2bf(f.w);
    dst[i] = u;
  }
}

// matvec: 4 rows/block, y = W@x + b over 1024 cols (W fp32)
__device__ __forceinline__ void mv4(const float* __restrict__ W, const float* __restrict__ x,
                                    const float* __restrict__ b, float* __restrict__ y,
                                    int blkrel, int tid) {
  int r = blkrel * 4 + (tid >> 6);
  int lane = tid & 63;
  float s = 0.f;
  for (int c = lane; c < 1024; c += 64) s += W[(size_t)r * 1024 + c] * x[c];
#pragma unroll
  for (int off = 32; off; off >>= 1) s += __shfl_down(s, off);
  if (lane == 0) y[r] = s + b[r];
}

// ---- K2: T^T (512x1024 bf16) = WvT @ Wiv^T, both operands staged from raw
// fp32 (A: transposing stage of Wv; B: straight cvt of Wiv). blocks [0,128).
// Tail: [128,384) matvec b1 = Wiv@bv+biv; [384,2432) cvt vit -> Xb.
__global__ __launch_bounds__(256) void k2_fused(const float* __restrict__ Wv,
                                                const float* __restrict__ Wiv,
                                                const float* __restrict__ bv,
                                                const float* __restrict__ biv,
                                                float* __restrict__ b1,
                                                unsigned short* __restrict__ Tt,
                                                const float* __restrict__ vit,
                                                unsigned short* __restrict__ Xb) {
  int bid = blockIdx.x, tid = threadIdx.x;
  if (bid >= 128) {
    int rel = bid - 128;
    if (rel < 256) mv4(Wiv, bv, biv, b1, rel, tid);
    else cvt4((const float4*)vit, (ushort4*)Xb, (rel - 256) * 1024 + tid);
    return;
  }
  __shared__ __align__(16) char Al0[64 * 128];
  __shared__ __align__(16) char Al1[64 * 128];
  __shared__ __align__(16) char Bl0[64 * 128];
  __shared__ __align__(16) char Bl1[64 * 128];
  const int bm0 = (bid >> 4) * 64, bn0 = (bid & 15) * 64;  // M=512, N=1024, nbn=16
  const int lane = tid & 63, wid = tid >> 6;
  const int wr = wid >> 1, wc = wid & 1, lr = lane & 15, kg = lane >> 4;

  v4f acc[2][2];
#pragma unroll
  for (int i = 0; i < 2; ++i)
#pragma unroll
    for (int j = 0; j < 2; ++j) acc[i][j] = 0.f;

  float4 ra[4], rb[4];
  // A-tile: Al[m][k] = Wv[kt+k][bm0+m] (ldf32 with row-base = kt, col-base = bm0)
  ldf32(Wv, 0, 512, bm0, tid, ra);
  ldf32(Wiv, bn0, 1024, 0, tid, rb);
  wrf32T(ra, Al0, tid);
  wrf32(rb, Bl0, tid);
  __syncthreads();

  for (int t = 0; t < 16; t += 2) {
    // t+1 <= 15 always
    ldf32(Wv, (t + 1) * 64, 512, bm0, tid, ra);
    ldf32(Wiv, bn0, 1024, (t + 1) * 64, tid, rb);
    __builtin_amdgcn_sched_barrier(0);
    compute_tile<64, 64, 64, 2, 2>(Al0, Bl0, acc, wr, wc, lr, kg);
    wrf32T(ra, Al1, tid);
    wrf32(rb, Bl1, tid);
    __syncthreads();

    if (t + 2 < 16) {
      ldf32(Wv, (t + 2) * 64, 512, bm0, tid, ra);
      ldf32(Wiv, bn0, 1024, (t + 2) * 64, tid, rb);
    }
    __builtin_amdgcn_sched_barrier(0);
    compute_tile<64, 64, 64, 2, 2>(Al1, Bl1, acc, wr, wc, lr, kg);
    if (t + 2 < 16) {
      wrf32T(ra, Al0, tid);
      wrf32(rb, Bl0, tid);
    }
    __syncthreads();
  }

#pragma unroll
  for (int ni = 0; ni < 2; ++ni) {
    int col = bn0 + wc * 32 + ni * 16 + lr;
#pragma unroll
    for (int mi = 0; mi < 2; ++mi) {
      int row0 = bm0 + wr * 32 + mi * 16 + kg * 4;
#pragma unroll
      for (int r = 0; r < 4; ++r)
        Tt[(size_t)(row0 + r) * 1024 + col] = f2bf(acc[mi][ni][r]);
    }
  }
}

// ---- K3: Wc (1024x512 bf16) = Wo @ T; A = Wo fp32 cvt-staged, B = Tt bf16
// via global_load_lds. blocks [0,128). Tail [128,384): bc = Wo@b1 + bo.
__global__ __launch_bounds__(256) void k3_fused(const float* __restrict__ Wo,
                                                const unsigned short* __restrict__ Tt,
                                                const float* __restrict__ b1,
                                                const float* __restrict__ bo,
                                                float* __restrict__ bc,
                                                unsigned short* __restrict__ Wc) {
  int bid = blockIdx.x, tid = threadIdx.x;
  if (bid >= 128) {
    mv4(Wo, b1, bo, bc, bid - 128, tid);
    return;
  }
  __shared__ __align__(16) char Al0[64 * 128];
  __shared__ __align__(16) char Al1[64 * 128];
  __shared__ __align__(16) char Bl0[64 * 128];
  __shared__ __align__(16) char Bl1[64 * 128];
  const int bm0 = (bid >> 3) * 64, bn0 = (bid & 7) * 64;  // M=1024, N=512, nbn=8
  const int lane = tid & 63, wid = tid >> 6;
  const int wr = wid >> 1, wc = wid & 1, lr = lane & 15, kg = lane >> 4;

  v4f acc[2][2];
#pragma unroll
  for (int i = 0; i < 2; ++i)
#pragma unroll
    for (int j = 0; j < 2; ++j) acc[i][j] = 0.f;

  float4 ra[4];
  ldf32(Wo, bm0, 1024, 0, tid, ra);
  stageg<64, 64>(Tt, bn0, 1024, 0, Bl0, wid, lane);
  wrf32(ra, Al0, tid);
  __syncthreads();

  for (int t = 0; t < 16; t += 2) {
    ldf32(Wo, bm0, 1024, (t + 1) * 64, tid, ra);
    stageg<64, 64>(Tt, bn0, 1024, (t + 1) * 64, Bl1, wid, lane);
    __builtin_amdgcn_sched_barrier(0);
    compute_tile<64, 64, 64, 2, 2>(Al0, Bl0, acc, wr, wc, lr, kg);
    wrf32(ra, Al1, tid);
    __syncthreads();

    if (t + 2 < 16) {
      ldf32(Wo, bm0, 1024, (t + 2) * 64, tid, ra);
      stageg<64, 64>(Tt, bn0, 1024, (t + 2) * 64, Bl0, wid, lane);
    }
    __builtin_amdgcn_sched_barrier(0);
    compute_tile<64, 64, 64, 2, 2>(Al1, Bl1, acc, wr, wc, lr, kg);
    if (t + 2 < 16) wrf32(ra, Al0, tid);
    __syncthreads();
  }

#pragma unroll
  for (int ni = 0; ni < 2; ++ni) {
    int col = bn0 + wc * 32 + ni * 16 + lr;
#pragma unroll
    for (int mi = 0; mi < 2; ++mi) {
      int row0 = bm0 + wr * 32 + mi * 16 + kg * 4;
#pragma unroll
      for (int r = 0; r < 4; ++r)
        Wc[(size_t)(row0 + r) * 512 + col] = f2bf(acc[mi][ni][r]);
    }
  }
}

// ---- K4 (R13-best): 128x128 tile, BK=64 (RB=128 swizzle, conflict-free),
// depth-2, NT=8 static. Phase t: vmcnt(8) [tile t+1 in flight]; barrier;
// setprio + 32 MFMA; barrier; stage tile t+2 into just-freed buffer.
__global__ __launch_bounds__(256) void gemm_k4(const unsigned short* __restrict__ A,
                                               const unsigned short* __restrict__ B,
                                               const float* __restrict__ bias,
                                               float* __restrict__ C,
                                               int M, int N, int K) {
  __shared__ __align__(16) char Al0[128 * 128];
  __shared__ __align__(16) char Al1[128 * 128];
  __shared__ __align__(16) char Bl0[128 * 128];
  __shared__ __align__(16) char Bl1[128 * 128];
  const int tid = threadIdx.x;
  const int lane = tid & 63, wid = tid >> 6;
  const int wr = wid >> 1, wc = wid & 1;
  const int lr = lane & 15, kg = lane >> 4;

  int bid = blockIdx.x;           // 1024 blocks, nbn = 8
  int x = bid & 7, j = bid >> 3;  // XCD row-band swizzle (proven)
  const int bm0 = (x + ((j >> 3) << 3)) * 128;
  const int bn0 = (j & 7) * 128;

  v4f acc[4][4];
#pragma unroll
  for (int i = 0; i < 4; ++i)
#pragma unroll
    for (int jj = 0; jj < 4; ++jj) acc[i][jj] = 0.f;

  stageg<128, 64>(A, bm0, K, 0, Al0, wid, lane);
  stageg<128, 64>(B, bn0, K, 0, Bl0, wid, lane);
  stageg<128, 64>(A, bm0, K, 64, Al1, wid, lane);
  stageg<128, 64>(B, bn0, K, 64, Bl1, wid, lane);

#define K4P(CA, CB, TN2, W)                                              \
  waitcnt_vm<W>();                                                       \
  __builtin_amdgcn_s_barrier();                                          \
  __builtin_amdgcn_sched_barrier(0);                                     \
  __builtin_amdgcn_s_setprio(1);                                         \
  compute_tile<128, 128, 64, 4, 4>(CA, CB, acc, wr, wc, lr, kg);         \
  __builtin_amdgcn_s_setprio(0);                                         \
  __builtin_amdgcn_sched_barrier(0);                                     \
  __builtin_amdgcn_s_barrier();                                          \
  if constexpr ((TN2) < 8) {                                             \
    stageg<128, 64>(A, bm0, K, (TN2)*64, CA, wid, lane);                 \
    stageg<128, 64>(B, bn0, K, (TN2)*64, CB, wid, lane);                 \
  }

  K4P(Al0, Bl0, 2, 8)   // t=0
  K4P(Al1, Bl1, 3, 8)   // t=1
  K4P(Al0, Bl0, 4, 8)   // t=2
  K4P(Al1, Bl1, 5, 8)   // t=3
  K4P(Al0, Bl0, 6, 8)   // t=4
  K4P(Al1, Bl1, 7, 8)   // t=5
  K4P(Al0, Bl0, 8, 8)   // t=6 (tile 7 in flight)
  K4P(Al1, Bl1, 8, 0)   // t=7 (drain)
#undef K4P

#pragma unroll
  for (int ni = 0; ni < 4; ++ni) {
    int col = bn0 + wc * 64 + ni * 16 + lr;
    float bz = bias[col];
#pragma unroll
    for (int mi = 0; mi < 4; ++mi) {
      int row0 = bm0 + wr * 64 + mi * 16 + kg * 4;
#pragma unroll
      for (int r = 0; r < 4; ++r)
        C[(size_t)(row0 + r) * N + col] = acc[mi][ni][r] + bz;
    }
  }
}

extern "C" void kernel_launch(void* const* d_in, const int* in_sizes, int n_in,
                              void* d_out, int out_size, void* d_ws, size_t ws_size,
                              hipStream_t stream) {
  // softmax over singleton axis == 1  =>  out = x @ (Wo·Wiv·Wv)^T + [Wo·(Wiv·bv+biv)+bo]
  const float* vit = (const float*)d_in[1];
  const float* Wv  = (const float*)d_in[6];
  const float* bv  = (const float*)d_in[7];
  const float* ipw = (const float*)d_in[8];
  const float* ipb = (const float*)d_in[9];
  const float* Wo  = (const float*)d_in[10];
  const float* bo  = (const float*)d_in[11];
  const float* Wiv = ipw + 2 * E_DIM * E_DIM;
  const float* biv = ipb + 2 * E_DIM;

  char* ws = (char*)d_ws;
  unsigned short* Xb  = (unsigned short*)(ws);               // 16384x512 bf16, 16 MB
  unsigned short* Ttb = (unsigned short*)(ws + (16 << 20));  // 512x1024 bf16 (T^T)
  unsigned short* Wcb = (unsigned short*)(ws + (17 << 20));  // 1024x512 bf16
  float* b1 = (float*)(ws + (18 << 20));
  float* bc = (float*)(ws + (18 << 20) + 4096);

  // K2: T^T GEMM from raw fp32 (128) || b1 matvec (256) || cvt vit (2048)
  k2_fused<<<2432, 256, 0, stream>>>(Wv, Wiv, bv, biv, b1, Ttb, vit, Xb);

  // K3: Wc = Wo @ T (128) || bc matvec (256)
  k3_fused<<<384, 256, 0, stream>>>(Wo, Ttb, b1, bo, bc, Wcb);

  // K4: out (16384x1024 f32) = Xb @ Wc^T + bc (BK=64 swizzled, depth-2, XCD swizzle)
  gemm_k4<<<1024, 256, 0, stream>>>(Xb, Wcb, bc, (float*)d_out, 16384, 1024, 512);
}